// Round 6
// baseline (373.908 us; speedup 1.0000x reference)
//
#include <hip/hip_runtime.h>

#define NTHREADS 256

typedef float v2f __attribute__((ext_vector_type(2)));

__device__ __forceinline__ int reflect128(int p) {
    p = (p < 0) ? (-p - 1) : p;
    p = (p >= 128) ? (255 - p) : p;
    return p;
}

// Per output phase j: 3 consecutive nonzero taps out of 5.
// cc0/cs0 apply to the G0-pair source (Yl or lh), cc1/cs1 to the G1-pair (hl or hh).
__constant__ int   cs0[4] = {2, 1, 1, 0};
__constant__ int   cs1[4] = {1, 2, 0, 1};
__constant__ float cc0[4][3] = {
    { 0.760272369066126f, -0.0883294244510729f,  0.0351638365171441f},
    { 0.233890320607236f,  0.587518297723561f,  -0.114301837144249f},
    {-0.114301837144249f,  0.587518297723561f,   0.233890320607236f},
    { 0.0351638365171441f, -0.0883294244510729f, 0.760272369066126f}};
__constant__ float cc1[4][3] = {
    { 0.233890320607236f,  0.587518297723561f,  -0.114301837144249f},
    {-0.760272369066126f,  0.0883294244510729f, -0.0351638365171441f},
    {-0.0351638365171441f, 0.0883294244510729f, -0.760272369066126f},
    {-0.114301837144249f,  0.587518297723561f,   0.233890320607236f}};

// min-waves hint 6: hint 8 capped allocator at 32 VGPR -> scratch spill, 3.3x
// slowdown (round 4). Reading Yl from global in the fused loop also leaks
// pressure into scratch traffic (round 5) -> Yl stays LDS-staged.
__global__ __launch_bounds__(NTHREADS, 6)
void dtcwt_inv_kernel(const float* __restrict__ Yl,
                      const float* __restrict__ Yhr,
                      const float* __restrict__ Yhi,
                      float* __restrict__ out)
{
    const int tid = threadIdx.x;

    // XCD-aware swizzle (FETCH 224->66 MB). Each XCD gets a contiguous run of
    // gidx = whole planes, so a plane's 16 tiles share one L2.
    const int bid  = blockIdx.x;
    const int perx = gridDim.x >> 3;               // blocks per XCD (grid % 8 == 0)
    const int gidx = (bid & 7) * perx + (bid >> 3);
    const int plane = gidx >> 4;                   // 0..511
    const int tile  = gidx & 15;
    const int ct = tile & 3;                       // col tile 0..3
    const int rt = tile >> 2;                      // row tile 0..3

    const int OR0 = rt * 64, OC0 = ct * 64;
    const int i0r = OR0 >> 2, i0c = OC0 >> 2;
    const int yrb = 2 * i0r - 4;    // raw first y row of the 40-row window (even)
    const int icb = 2 * i0c - 4;    // raw first input col of the 40-col window (even)

    const float* yl = Yl + (size_t)plane * (128 * 128);
    const float* hr = Yhr + (size_t)plane * 6 * 4096;
    const float* hi = Yhi + (size_t)plane * 6 * 4096;

    // Packed-by-read-offset staging (f32, natural order), 25.6 KB -> 6 blocks/CU:
    //   sP[t][u] = (Yl, Lh)  -- both read at u-offset ub0 (G0 taps)
    //   sQ[t][u] = (Hl, Hh)  -- both read at u-offset ub1 (G1 taps)
    // y1 = P.x*a + Q.x*b ; y2 = P.y*a + Q.y*b with the SAME a,b coefficients
    // -> Phase B is v_pk_fma_f32-shaped on (y1,y2) pairs.
    __shared__ v2f sP[40][40];
    __shared__ v2f sQ[40][40];

    const float RS2 = 0.70710678118654752440f;  // 1/sqrt(2)

    // ---- Phase A1: stage Yl window into sP[.].x, float2 col-pairs (static). ----
    // Raw col pair (even,odd); reflection maps it to a swapped even-based pair.
#pragma unroll
    for (int k = 0; k < 4; ++k) {
        const int e = tid + k * NTHREADS;      // 0..1023; need e < 800
        if (k == 3 && e >= 800) break;
        const int t  = e / 20;                 // staged row 0..39
        const int u2 = e - t * 20;             // col-pair 0..19
        const int ry = reflect128(yrb + t);
        const int cr0 = icb + 2 * u2;          // even raw col of the pair
        int base; int swap;
        if (cr0 < 0)        { base = -cr0 - 2;  swap = 1; }
        else if (cr0 > 126) { base = 254 - cr0; swap = 1; }
        else                { base = cr0;       swap = 0; }
        const float2 v = *(const float2*)(yl + ry * 128 + base);
        sP[t][2 * u2].x     = swap ? v.y : v.x;
        sP[t][2 * u2 + 1].x = swap ? v.x : v.y;
    }

    // ---- Phase A2: c2q staging; 2 statically-assigned quads/thread, all global
    //      loads issued before the dependent math (load ILP). ----
    {
        const int e0 = tid;              // always < 400
        const int e1 = tid + NTHREADS;   // valid for tid < 144
        const int has1 = (e1 < 400);

        const int t2a = e0 / 20, u2a = e0 - t2a * 20;
        const int ara = i0r - 2 + t2a, aca = i0c - 2 + u2a;
        const int oobra = (ara < 0) | (ara >= 64);
        const int oobca = (aca < 0) | (aca >= 64);
        const int r2a = oobra ? ((ara < 0) ? (-ara - 1) : (127 - ara)) : ara;
        const int c2a = oobca ? ((aca < 0) ? (-aca - 1) : (127 - aca)) : aca;
        const int offa = r2a * 64 + c2a;

        const int e1c = has1 ? e1 : 0;
        const int t2b = e1c / 20, u2b = e1c - t2b * 20;
        const int arb = i0r - 2 + t2b, acb = i0c - 2 + u2b;
        const int oobrb = (arb < 0) | (arb >= 64);
        const int oobcb = (acb < 0) | (acb >= 64);
        const int r2b = oobrb ? ((arb < 0) ? (-arb - 1) : (127 - arb)) : arb;
        const int c2b = oobcb ? ((acb < 0) ? (-acb - 1) : (127 - acb)) : acb;
        const int offb = r2b * 64 + c2b;

        float Ra[6], Ia[6], Rb[6], Ib[6];
#pragma unroll
        for (int k = 0; k < 6; ++k) { Ra[k] = hr[k * 4096 + offa]; Ia[k] = hi[k * 4096 + offa]; }
#pragma unroll
        for (int k = 0; k < 6; ++k) { Rb[k] = hr[k * 4096 + offb]; Ib[k] = hi[k * 4096 + offb]; }

#pragma unroll
        for (int wq = 0; wq < 2; ++wq) {
            if (wq == 1 && !has1) break;
            const float* R = (wq == 0) ? Ra : Rb;
            const float* I = (wq == 0) ? Ia : Ib;
            const int t2 = (wq == 0) ? t2a : t2b;
            const int u2 = (wq == 0) ? u2a : u2b;
            const int oobr = (wq == 0) ? oobra : oobrb;
            const int oobc = (wq == 0) ? oobca : oobcb;
#pragma unroll
            for (int dt = 0; dt < 2; ++dt) {
#pragma unroll
                for (int du = 0; du < 2; ++du) {
                    const int p = dt ^ oobr;            // reflection flips sample parity
                    const int q = du ^ oobc;
                    const float sA = (p & q) ? -RS2 : RS2;
                    const float sB = (p & (q ^ 1)) ? -RS2 : RS2;
                    float b0, b5, b2v, b3, b1, b4;
                    if (p == q) { b0 = R[0]; b5 = R[5]; b2v = R[2]; b3 = R[3]; b1 = R[1]; b4 = R[4]; }
                    else        { b0 = I[0]; b5 = I[5]; b2v = I[2]; b3 = I[3]; b1 = I[1]; b4 = I[4]; }
                    const int t = 2 * t2 + dt, u = 2 * u2 + du;
                    sP[t][u].y = sA * b0 + sB * b5;                      // Lh
                    v2f qv; qv.x = sA * b2v + sB * b3;                   // Hl
                    qv.y = sA * b1 + sB * b4;                            // Hh
                    sQ[t][u] = qv;
                }
            }
        }
    }
    __syncthreads();

    // ---- Phase B (packed) + C fused: thread owns one column + 16-row strip. ----
    const int c  = tid & 63;        // output column within tile
    const int g  = tid >> 6;        // 16-row output strip
    const int jc = c & 3;
    const int q2 = c >> 2;
    const float a0  = cc0[jc][0], a1  = cc0[jc][1], a2  = cc0[jc][2];
    const float b0w = cc1[jc][0], b1w = cc1[jc][1], b2w = cc1[jc][2];
    const int ub0 = 2 * q2 + (jc & 1) + 2 * cs0[jc];          // first G0 tap col (u)
    const int ub1 = 2 * q2 + ((jc & 1) ^ 1) + 2 * cs1[jc];    // first G1 tap col

    const int tb = 8 * g;           // y rows needed: [tb+1, tb+14]
    v2f y12[14];                    // (y1, y2) pairs -> v_pk_fma_f32 candidates
#pragma unroll
    for (int k = 0; k < 14; ++k) {
        const int t = tb + 1 + k;
        const v2f P0 = sP[t][ub0], P1 = sP[t][ub0 + 2], P2 = sP[t][ub0 + 4];
        const v2f Q0 = sQ[t][ub1], Q1 = sQ[t][ub1 + 2], Q2 = sQ[t][ub1 + 4];
        y12[k] = P0 * a0 + P1 * a1 + P2 * a2
               + Q0 * b0w + Q1 * b1w + Q2 * b2w;
    }

    float* op = out + ((size_t)plane * 256 + OR0 + 16 * g) * 256 + OC0 + c;
#pragma unroll
    for (int j = 0; j < 4; ++j) {
        const int p0 = j & 1, p1 = p0 ^ 1;
        const int r0 = p0 + 2 * cs0[j];   // y1 tap rows: 2m + r0 + {0,2,4}
        const int r1 = p1 + 2 * cs1[j];
        const float d0 = cc0[j][0], d1 = cc0[j][1], d2 = cc0[j][2];
        const float e0 = cc1[j][0], e1 = cc1[j][1], e2 = cc1[j][2];
#pragma unroll
        for (int mm = 0; mm < 4; ++mm) {
            const int k0 = 2 * mm + r0 - 1;
            const int k1 = 2 * mm + r1 - 1;
            const float acc = y12[k0].x * d0 + y12[k0 + 2].x * d1 + y12[k0 + 4].x * d2
                            + y12[k1].y * e0 + y12[k1 + 2].y * e1 + y12[k1 + 4].y * e2;
            op[(size_t)(4 * mm + j) * 256] = acc;
        }
    }
}

extern "C" void kernel_launch(void* const* d_in, const int* in_sizes, int n_in,
                              void* d_out, int out_size, void* d_ws, size_t ws_size,
                              hipStream_t stream) {
    const float* Yl  = (const float*)d_in[0];
    const float* Yhr = (const float*)d_in[1];
    const float* Yhi = (const float*)d_in[2];
    float* out = (float*)d_out;

    const int planes = in_sizes[0] / (128 * 128);   // B*C = 512
    dim3 grid(planes * 16, 1, 1);
    dtcwt_inv_kernel<<<grid, NTHREADS, 0, stream>>>(Yl, Yhr, Yhi, out);
}

// Round 7
// 254.175 us; speedup vs baseline: 1.4711x; 1.4711x over previous
//
#include <hip/hip_runtime.h>

#define NTHREADS 256

typedef float v2f __attribute__((ext_vector_type(2)));

__device__ __forceinline__ int reflect128(int p) {
    p = (p < 0) ? (-p - 1) : p;
    p = (p >= 128) ? (255 - p) : p;
    return p;
}

// Per output phase j: 3 consecutive nonzero taps out of 5.
// cc0/cs0 apply to the G0-pair source (Yl or lh), cc1/cs1 to the G1-pair (hl or hh).
// TWO copies of the tables:
//  - __constant__ for runtime (per-lane jc) indexing in Phase B.
//  - constexpr for compile-time (unrolled j) indexing in Phase C. __constant__ is
//    externally_initialized -> NOT foldable -> runtime k0 -> scratch (round 6, rule #20).
__constant__ int   cs0[4] = {2, 1, 1, 0};
__constant__ int   cs1[4] = {1, 2, 0, 1};
__constant__ float cc0[4][3] = {
    { 0.760272369066126f, -0.0883294244510729f,  0.0351638365171441f},
    { 0.233890320607236f,  0.587518297723561f,  -0.114301837144249f},
    {-0.114301837144249f,  0.587518297723561f,   0.233890320607236f},
    { 0.0351638365171441f, -0.0883294244510729f, 0.760272369066126f}};
__constant__ float cc1[4][3] = {
    { 0.233890320607236f,  0.587518297723561f,  -0.114301837144249f},
    {-0.760272369066126f,  0.0883294244510729f, -0.0351638365171441f},
    {-0.0351638365171441f, 0.0883294244510729f, -0.760272369066126f},
    {-0.114301837144249f,  0.587518297723561f,   0.233890320607236f}};

static constexpr int   kcs0[4] = {2, 1, 1, 0};
static constexpr int   kcs1[4] = {1, 2, 0, 1};
static constexpr float kcc0[4][3] = {
    { 0.760272369066126f, -0.0883294244510729f,  0.0351638365171441f},
    { 0.233890320607236f,  0.587518297723561f,  -0.114301837144249f},
    {-0.114301837144249f,  0.587518297723561f,   0.233890320607236f},
    { 0.0351638365171441f, -0.0883294244510729f, 0.760272369066126f}};
static constexpr float kcc1[4][3] = {
    { 0.233890320607236f,  0.587518297723561f,  -0.114301837144249f},
    {-0.760272369066126f,  0.0883294244510729f, -0.0351638365171441f},
    {-0.0351638365171441f, 0.0883294244510729f, -0.760272369066126f},
    {-0.114301837144249f,  0.587518297723561f,   0.233890320607236f}};

// min-waves hint 6: hint 8 capped allocator at 32 VGPR -> scratch spill, 3.3x
// slowdown (round 4). Yl stays LDS-staged (global-read variant leaked scratch, round 5).
__global__ __launch_bounds__(NTHREADS, 6)
void dtcwt_inv_kernel(const float* __restrict__ Yl,
                      const float* __restrict__ Yhr,
                      const float* __restrict__ Yhi,
                      float* __restrict__ out)
{
    const int tid = threadIdx.x;

    // XCD-aware swizzle (FETCH 224->66 MB). Each XCD gets a contiguous run of
    // gidx = whole planes, so a plane's 16 tiles share one L2.
    const int bid  = blockIdx.x;
    const int perx = gridDim.x >> 3;               // blocks per XCD (grid % 8 == 0)
    const int gidx = (bid & 7) * perx + (bid >> 3);
    const int plane = gidx >> 4;                   // 0..511
    const int tile  = gidx & 15;
    const int ct = tile & 3;                       // col tile 0..3
    const int rt = tile >> 2;                      // row tile 0..3

    const int OR0 = rt * 64, OC0 = ct * 64;
    const int i0r = OR0 >> 2, i0c = OC0 >> 2;
    const int yrb = 2 * i0r - 4;    // raw first y row of the 40-row window (even)
    const int icb = 2 * i0c - 4;    // raw first input col of the 40-col window (even)

    const float* yl = Yl + (size_t)plane * (128 * 128);
    const float* hr = Yhr + (size_t)plane * 6 * 4096;
    const float* hi = Yhi + (size_t)plane * 6 * 4096;

    // Packed-by-read-offset staging (f32, natural order), 25.6 KB -> 6 blocks/CU:
    //   sP[t][u] = (Yl, Lh)  -- both read at u-offset ub0 (G0 taps)
    //   sQ[t][u] = (Hl, Hh)  -- both read at u-offset ub1 (G1 taps)
    __shared__ v2f sP[40][40];
    __shared__ v2f sQ[40][40];

    const float RS2 = 0.70710678118654752440f;  // 1/sqrt(2)

    // ---- Phase A1: stage Yl window into sP[.].x, float2 col-pairs (static). ----
    // Raw col pair (even,odd); reflection maps it to a swapped even-based pair.
#pragma unroll
    for (int k = 0; k < 4; ++k) {
        const int e = tid + k * NTHREADS;      // 0..1023; need e < 800
        if (k == 3 && e >= 800) break;
        const int t  = e / 20;                 // staged row 0..39
        const int u2 = e - t * 20;             // col-pair 0..19
        const int ry = reflect128(yrb + t);
        const int cr0 = icb + 2 * u2;          // even raw col of the pair
        int base; int swap;
        if (cr0 < 0)        { base = -cr0 - 2;  swap = 1; }
        else if (cr0 > 126) { base = 254 - cr0; swap = 1; }
        else                { base = cr0;       swap = 0; }
        const float2 v = *(const float2*)(yl + ry * 128 + base);
        sP[t][2 * u2].x     = swap ? v.y : v.x;
        sP[t][2 * u2 + 1].x = swap ? v.x : v.y;
    }

    // ---- Phase A2: c2q staging; 2 statically-assigned quads/thread, all global
    //      loads issued before the dependent math (load ILP). ----
    {
        const int e0 = tid;              // always < 400
        const int e1 = tid + NTHREADS;   // valid for tid < 144
        const int has1 = (e1 < 400);

        const int t2a = e0 / 20, u2a = e0 - t2a * 20;
        const int ara = i0r - 2 + t2a, aca = i0c - 2 + u2a;
        const int oobra = (ara < 0) | (ara >= 64);
        const int oobca = (aca < 0) | (aca >= 64);
        const int r2a = oobra ? ((ara < 0) ? (-ara - 1) : (127 - ara)) : ara;
        const int c2a = oobca ? ((aca < 0) ? (-aca - 1) : (127 - aca)) : aca;
        const int offa = r2a * 64 + c2a;

        const int e1c = has1 ? e1 : 0;
        const int t2b = e1c / 20, u2b = e1c - t2b * 20;
        const int arb = i0r - 2 + t2b, acb = i0c - 2 + u2b;
        const int oobrb = (arb < 0) | (arb >= 64);
        const int oobcb = (acb < 0) | (acb >= 64);
        const int r2b = oobrb ? ((arb < 0) ? (-arb - 1) : (127 - arb)) : arb;
        const int c2b = oobcb ? ((acb < 0) ? (-acb - 1) : (127 - acb)) : acb;
        const int offb = r2b * 64 + c2b;

        float Ra[6], Ia[6], Rb[6], Ib[6];
#pragma unroll
        for (int k = 0; k < 6; ++k) { Ra[k] = hr[k * 4096 + offa]; Ia[k] = hi[k * 4096 + offa]; }
#pragma unroll
        for (int k = 0; k < 6; ++k) { Rb[k] = hr[k * 4096 + offb]; Ib[k] = hi[k * 4096 + offb]; }

#pragma unroll
        for (int wq = 0; wq < 2; ++wq) {
            if (wq == 1 && !has1) break;
            const float* R = (wq == 0) ? Ra : Rb;
            const float* I = (wq == 0) ? Ia : Ib;
            const int t2 = (wq == 0) ? t2a : t2b;
            const int u2 = (wq == 0) ? u2a : u2b;
            const int oobr = (wq == 0) ? oobra : oobrb;
            const int oobc = (wq == 0) ? oobca : oobcb;
#pragma unroll
            for (int dt = 0; dt < 2; ++dt) {
#pragma unroll
                for (int du = 0; du < 2; ++du) {
                    const int p = dt ^ oobr;            // reflection flips sample parity
                    const int q = du ^ oobc;
                    const float sA = (p & q) ? -RS2 : RS2;
                    const float sB = (p & (q ^ 1)) ? -RS2 : RS2;
                    float b0, b5, b2v, b3, b1, b4;
                    if (p == q) { b0 = R[0]; b5 = R[5]; b2v = R[2]; b3 = R[3]; b1 = R[1]; b4 = R[4]; }
                    else        { b0 = I[0]; b5 = I[5]; b2v = I[2]; b3 = I[3]; b1 = I[1]; b4 = I[4]; }
                    const int t = 2 * t2 + dt, u = 2 * u2 + du;
                    sP[t][u].y = sA * b0 + sB * b5;                      // Lh
                    v2f qv; qv.x = sA * b2v + sB * b3;                   // Hl
                    qv.y = sA * b1 + sB * b4;                            // Hh
                    sQ[t][u] = qv;
                }
            }
        }
    }
    __syncthreads();

    // ---- Phase B (packed, loop-local v2f only) + C fused. ----
    const int c  = tid & 63;        // output column within tile
    const int g  = tid >> 6;        // 16-row output strip
    const int jc = c & 3;
    const int q2 = c >> 2;
    const float a0  = cc0[jc][0], a1  = cc0[jc][1], a2  = cc0[jc][2];
    const float b0w = cc1[jc][0], b1w = cc1[jc][1], b2w = cc1[jc][2];
    const int ub0 = 2 * q2 + (jc & 1) + 2 * cs0[jc];          // first G0 tap col (u)
    const int ub1 = 2 * q2 + ((jc & 1) ^ 1) + 2 * cs1[jc];    // first G1 tap col

    const int tb = 8 * g;           // y rows needed: [tb+1, tb+14]
    float y1v[14], y2v[14];         // scalar arrays: known-good (R3); v2f array spilled (R6)
#pragma unroll
    for (int k = 0; k < 14; ++k) {
        const int t = tb + 1 + k;
        const v2f acc = sP[t][ub0] * a0  + sP[t][ub0 + 2] * a1  + sP[t][ub0 + 4] * a2
                      + sQ[t][ub1] * b0w + sQ[t][ub1 + 2] * b1w + sQ[t][ub1 + 4] * b2w;
        y1v[k] = acc.x;
        y2v[k] = acc.y;
    }

    float* op = out + ((size_t)plane * 256 + OR0 + 16 * g) * 256 + OC0 + c;
#pragma unroll
    for (int j = 0; j < 4; ++j) {
        constexpr int P0c[4] = {0, 1, 0, 1};
        const int p0 = P0c[j], p1 = p0 ^ 1;
        const int r0 = p0 + 2 * kcs0[j];   // compile-time: constexpr table
        const int r1 = p1 + 2 * kcs1[j];
        const float d0 = kcc0[j][0], d1 = kcc0[j][1], d2 = kcc0[j][2];
        const float e0 = kcc1[j][0], e1 = kcc1[j][1], e2 = kcc1[j][2];
#pragma unroll
        for (int mm = 0; mm < 4; ++mm) {
            const int k0 = 2 * mm + r0 - 1;    // literal after unroll
            const int k1 = 2 * mm + r1 - 1;
            const float acc = y1v[k0] * d0 + y1v[k0 + 2] * d1 + y1v[k0 + 4] * d2
                            + y2v[k1] * e0 + y2v[k1 + 2] * e1 + y2v[k1 + 4] * e2;
            op[(size_t)(4 * mm + j) * 256] = acc;
        }
    }
}

extern "C" void kernel_launch(void* const* d_in, const int* in_sizes, int n_in,
                              void* d_out, int out_size, void* d_ws, size_t ws_size,
                              hipStream_t stream) {
    const float* Yl  = (const float*)d_in[0];
    const float* Yhr = (const float*)d_in[1];
    const float* Yhi = (const float*)d_in[2];
    float* out = (float*)d_out;

    const int planes = in_sizes[0] / (128 * 128);   // B*C = 512
    dim3 grid(planes * 16, 1, 1);
    dtcwt_inv_kernel<<<grid, NTHREADS, 0, stream>>>(Yl, Yhr, Yhi, out);
}